// Round 18
// baseline (114.696 us; speedup 1.0000x reference)
//
#include <hip/hip_runtime.h>
#include <hip/hip_fp16.h>

// PQ sim: sim = decode(x) @ decode(tgt)^T via i8 GEMM (K=512, exact int32
// accumulate; global symmetric scale s = 127/max|cen| measured on device).
// R18: R17 + launch-time phase stagger. Co-resident blocks get phase class
// (bid>>3)%3 and spin 0/4.5/9 us on s_memrealtime before the prologue, so
// epilogue write bursts de-phase across the 3 blocks/CU and overlap sibling
// compute (write channel was idle ~43% of the GEMM timeline when in-phase).
// Ring-of-3 (48 KB) + vmcnt(4), XOR swizzle, setprio, XCD-pinned supertiles.

#define D_FULL 512
#define M_SUB 64
#define KSUB 256
#define DSUB 8
#define KPB 512  // bytes per row (512 i8)

typedef int i32x4 __attribute__((ext_vector_type(4)));

static __device__ __forceinline__ unsigned int pack4i8(float a, float b,
                                                       float c, float d,
                                                       float s) {
  int q0 = (int)rintf(a * s), q1 = (int)rintf(b * s);
  int q2 = (int)rintf(c * s), q3 = (int)rintf(d * s);
  return (unsigned int)(q0 & 0xff) | ((unsigned int)(q1 & 0xff) << 8) |
         ((unsigned int)(q2 & 0xff) << 16) | ((unsigned int)(q3 & 0xff) << 24);
}

static __device__ __forceinline__ float scale_from(const float* part) {
  float m = 0.f;
#pragma unroll
  for (int i = 0; i < 64; ++i) m = fmaxf(m, part[i]);
  return 127.0f / m;
}

// ---------------- pass 0: per-block max|cen| (64 partials) ----------------
__global__ void max_kernel(const float* __restrict__ cen,
                           float* __restrict__ part) {
  const int t = threadIdx.x;
  const int i = (blockIdx.x * 256 + t) * 8;
  float4 a = *(const float4*)(cen + i);
  float4 b = *(const float4*)(cen + i + 4);
  float m = fmaxf(fmaxf(fmaxf(fabsf(a.x), fabsf(a.y)),
                        fmaxf(fabsf(a.z), fabsf(a.w))),
                  fmaxf(fmaxf(fabsf(b.x), fabsf(b.y)),
                        fmaxf(fabsf(b.z), fabsf(b.w))));
  __shared__ float wm[4];
  for (int off = 32; off; off >>= 1) m = fmaxf(m, __shfl_down(m, off, 64));
  if ((t & 63) == 0) wm[t >> 6] = m;
  __syncthreads();
  if (t == 0)
    part[blockIdx.x] = fmaxf(fmaxf(wm[0], wm[1]), fmaxf(wm[2], wm[3]));
}

// ---------------- encode queries -> A' (i8), Q=4, exact f32 argmin ----------
__global__ void encode_kernel(const float* __restrict__ x,
                              const float* __restrict__ cen,
                              signed char* __restrict__ Ap,
                              const float* __restrict__ part) {
  __shared__ float cs[KSUB][DSUB];
  __shared__ float n2[KSUB];
  const int t = threadIdx.x;
  const int sub = blockIdx.x;
  const int i0 = blockIdx.y * 1024 + t;

  const float* cp = cen + ((size_t)sub * KSUB + t) * DSUB;
  float4 c0 = *(const float4*)cp;
  float4 c1 = *(const float4*)(cp + 4);
  *(float4*)&cs[t][0] = c0;
  *(float4*)&cs[t][4] = c1;
  n2[t] = c0.x * c0.x + c0.y * c0.y + c0.z * c0.z + c0.w * c0.w +
          c1.x * c1.x + c1.y * c1.y + c1.z * c1.z + c1.w * c1.w;
  __syncthreads();

  float xq[4][8];
#pragma unroll
  for (int q = 0; q < 4; ++q) {
    const float* xp = x + (size_t)(i0 + q * 256) * D_FULL + sub * DSUB;
    *(float4*)&xq[q][0] = *(const float4*)xp;
    *(float4*)&xq[q][4] = *(const float4*)(xp + 4);
  }

  float best[4] = {1e30f, 1e30f, 1e30f, 1e30f};
  int bk[4] = {0, 0, 0, 0};
#pragma unroll 4
  for (int k = 0; k < KSUB; ++k) {
    float c[8];
    *(float4*)&c[0] = *(const float4*)&cs[k][0];
    *(float4*)&c[4] = *(const float4*)&cs[k][4];
    const float nn = n2[k];
#pragma unroll
    for (int q = 0; q < 4; ++q) {
      float dot = 0.f;
#pragma unroll
      for (int d = 0; d < 8; ++d) dot += c[d] * xq[q][d];
      float dis = nn - 2.0f * dot;
      if (dis < best[q]) { best[q] = dis; bk[q] = k; }  // strict < = numpy tie
    }
  }

  const float s = scale_from(part);
#pragma unroll
  for (int q = 0; q < 4; ++q) {
    const int b = bk[q];
    uint2 v;
    v.x = pack4i8(cs[b][0], cs[b][1], cs[b][2], cs[b][3], s);
    v.y = pack4i8(cs[b][4], cs[b][5], cs[b][6], cs[b][7], s);
    *(uint2*)(Ap + (size_t)(i0 + q * 256) * KPB + sub * DSUB) = v;
  }
}

// ---------------- decode targets -> B' (i8) ----------------
__global__ void decode_tgt(const int* __restrict__ tgt,
                           const float* __restrict__ cen,
                           signed char* __restrict__ Bp,
                           const float* __restrict__ part) {
  int g = blockIdx.x * 256 + threadIdx.x;
  int j = g >> 6, sub = g & 63;
  int k = tgt[g];
  const float* c = cen + ((size_t)sub * KSUB + k) * DSUB;
  float4 v0 = *(const float4*)c;
  float4 v1 = *(const float4*)(c + 4);
  const float s = scale_from(part);
  uint2 v;
  v.x = pack4i8(v0.x, v0.y, v0.z, v0.w, s);
  v.y = pack4i8(v1.x, v1.y, v1.z, v1.w, s);
  *(uint2*)(Bp + (size_t)j * KPB + sub * DSUB) = v;
}

// ---------------- GEMM: C = (A'q . B'q^T) / s^2 ----------------
// Slot (16 KB): A 128x64 i8 (8 KB) + B 128x64 i8 (8 KB). Row = 64 B =
// 4 chunks of 16 B. Phys chunk p at row r holds logical chunk p^(r&3)
// (stage: linear dest + inverse-swizzled global source, rule #21).
#define GLL(SRC, DST)                                                          \
  __builtin_amdgcn_global_load_lds(                                            \
      (const __attribute__((address_space(1))) void*)(SRC),                    \
      (__attribute__((address_space(3))) void*)(DST), 16, 0, 0)

#define STAGE(K0, SLOT)                                                        \
  do {                                                                         \
    signed char* as_ = lds + (SLOT)*16384;                                     \
    signed char* bs_ = as_ + 8192;                                             \
    _Pragma("unroll") for (int it = 0; it < 2; ++it) {                         \
      int r = it * 64 + (tid >> 2);                                            \
      int c = (tid & 3) ^ (r & 3);                                             \
      GLL(Ab + (size_t)r * KPB + (K0) + c * 16, as_ + it * 4096 + tid * 16);   \
    }                                                                          \
    _Pragma("unroll") for (int it = 0; it < 2; ++it) {                         \
      int r = it * 64 + (tid >> 2);                                            \
      int c = (tid & 3) ^ (r & 3);                                             \
      GLL(Bb + (size_t)r * KPB + (K0) + c * 16, bs_ + it * 4096 + tid * 16);   \
    }                                                                          \
  } while (0)

// One BK=64 step from SLOT: 8 ds_read_b128 + 16 MFMA i8 (K=64) per wave.
#define COMPUTE(SLOT)                                                          \
  do {                                                                         \
    const signed char* as_ = lds + (SLOT)*16384;                               \
    const signed char* bs_ = as_ + 8192;                                       \
    const int kq = l >> 4;                                                     \
    i32x4 a_[4], b_[4];                                                        \
    _Pragma("unroll") for (int i2 = 0; i2 < 4; ++i2) {                         \
      int row = wm * 64 + i2 * 16 + (l & 15);                                  \
      a_[i2] = *(const i32x4*)&as_[row * 64 + ((kq ^ (row & 3)) * 16)];        \
    }                                                                          \
    _Pragma("unroll") for (int j2 = 0; j2 < 4; ++j2) {                         \
      int row = wn * 64 + j2 * 16 + (l & 15);                                  \
      b_[j2] = *(const i32x4*)&bs_[row * 64 + ((kq ^ (row & 3)) * 16)];        \
    }                                                                          \
    __builtin_amdgcn_s_setprio(1);                                             \
    _Pragma("unroll") for (int i2 = 0; i2 < 4; ++i2)                           \
        _Pragma("unroll") for (int j2 = 0; j2 < 4; ++j2) acc[i2][j2] =         \
        __builtin_amdgcn_mfma_i32_16x16x64_i8(a_[i2], b_[j2], acc[i2][j2], 0,  \
                                              0, 0);                           \
    __builtin_amdgcn_s_setprio(0);                                             \
  } while (0)

#define VMW(N) asm volatile("s_waitcnt vmcnt(" #N ")" ::: "memory")
#define BAR() __builtin_amdgcn_s_barrier()

__global__ __launch_bounds__(256, 3) void gemm_i8(
    const signed char* __restrict__ A, const signed char* __restrict__ B,
    float* __restrict__ C, int Nt, const float* __restrict__ part) {
  __shared__ signed char lds[3 * 16384];  // 48 KB ring-of-3 -> 3 blocks/CU
  const int tid = threadIdx.x;
  const int w = tid >> 6, l = tid & 63;
  const int wm = w >> 1, wn = w & 1;  // 2M x 2N -> wave tile 64x64

  // XCD-pinned mapping: XCD x owns bn-stripe [x*16, x*16+16) (1 MB B i8,
  // L2-resident). Within XCD walk 4bm x 16bn supertiles bm-fastest.
  const int bid = blockIdx.x;
  const int xcd = bid & 7;
  const int idx = bid >> 3;                     // 0..511 per XCD
  const int sup = idx >> 6, loc = idx & 63;
  const int bm = sup * 4 + (loc & 3);           // 0..31
  const int bn = xcd * 16 + ((loc >> 2) & 15);  // 0..127

  // R18: phase stagger — break co-resident blocks' epilogue phase-lock.
  // Classes 0/1/2 spin 0/4.5/9 us (s_memrealtime = 100 MHz -> 450 ticks/cls).
  {
    const int ph = (bid >> 3) % 3;
    if (ph) {
      const long long tgt = (long long)ph * 450;
      const long long t0 = __builtin_amdgcn_s_memrealtime();
      while (__builtin_amdgcn_s_memrealtime() - t0 < tgt) {
      }
    }
  }

  const signed char* Ab = A + (size_t)bm * 128 * KPB;
  const signed char* Bb = B + (size_t)bn * 128 * KPB;

  i32x4 acc[4][4] = {};

  // Ring-of-3, depth-2 prefetch, 4 loads/thread/tile (tile t in slot t%3).
  STAGE(0, 0);
  STAGE(64, 1);
  VMW(4);  // drain tile0's 4, leave tile1's 4 in flight
  BAR();

  // Step t: stage tile t+2 into slot (t+2)%3 (freed at step t-1's barrier),
  // compute tile t, drain tile t+1's 4 loads (leave t+2's 4 in flight).
  STAGE(128, 2); COMPUTE(0); VMW(4); BAR();  // t=0
  STAGE(192, 0); COMPUTE(1); VMW(4); BAR();  // t=1
  STAGE(256, 1); COMPUTE(2); VMW(4); BAR();  // t=2
  STAGE(320, 2); COMPUTE(0); VMW(4); BAR();  // t=3
  STAGE(384, 0); COMPUTE(1); VMW(4); BAR();  // t=4
  STAGE(448, 1); COMPUTE(2); VMW(4); BAR();  // t=5
  COMPUTE(0); VMW(0); BAR();                 // t=6 (drain tile 7)
  COMPUTE(1);                                // t=7

  // Epilogue: sim = acc * (max/127)^2. C/D layout col=lane&15,
  // row=(lane>>4)*4+reg (dtype-independent, m121-128).
  const float minv = 1.0f / scale_from(part);  // = max/127
  const float inv = minv * minv;
  const int rb = bm * 128 + wm * 64 + (l >> 4) * 4;
  const int cb = bn * 128 + wn * 64 + (l & 15);
#pragma unroll
  for (int i2 = 0; i2 < 4; ++i2)
#pragma unroll
    for (int j2 = 0; j2 < 4; ++j2)
#pragma unroll
      for (int r = 0; r < 4; ++r)
        C[(size_t)(rb + i2 * 16 + r) * Nt + cb + j2 * 16] =
            (float)acc[i2][j2][r] * inv;
}

extern "C" void kernel_launch(void* const* d_in, const int* in_sizes, int n_in,
                              void* d_out, int out_size, void* d_ws, size_t ws_size,
                              hipStream_t stream) {
  const float* x = (const float*)d_in[0];    // [n, 512]
  const float* cen = (const float*)d_in[1];  // [64, 256, 8]
  const int* tgt = (const int*)d_in[2];      // [m, 64]
  float* out = (float*)d_out;                // [n, m]
  const int n = in_sizes[0] / D_FULL;        // 4096
  const int m = in_sizes[2] / M_SUB;         // 16384

  signed char* Ap = (signed char*)d_ws;            // [n, 512] i8
  signed char* Bp = Ap + (size_t)n * KPB;          // [m, 512] i8
  float* part = (float*)(Bp + (size_t)m * KPB);    // [64] partial maxes

  max_kernel<<<dim3(64), 256, 0, stream>>>(cen, part);
  encode_kernel<<<dim3(M_SUB, n / 1024), 256, 0, stream>>>(x, cen, Ap, part);
  decode_tgt<<<dim3((m * M_SUB) / 256), 256, 0, stream>>>(tgt, cen, Bp, part);
  gemm_i8<<<dim3((n / 128) * (m / 128)), 256, 0, stream>>>(Ap, Bp, out, m, part);
}

// Round 19
// 108.640 us; speedup vs baseline: 1.0557x; 1.0557x over previous
//
#include <hip/hip_runtime.h>
#include <hip/hip_fp16.h>

// PQ sim: sim = decode(x) @ decode(tgt)^T via i8 GEMM (K=512, exact int32
// accumulate; global symmetric scale s = 127/max|cen| measured on device).
// R19: last untested (LDS-ratio x occupancy) cell: BM=256 BN=128, 4 waves
// (2Mx2N, wave tile 128x64 -> 0.375 LDS-reads/MFMA, -25% vs R17), ring-of-3
// (72 KB) + counted vmcnt(6) -> 2 blocks/CU. No stagger (R18 falsified).
// XOR chunk swizzle (rule #21), setprio, XCD-pinned supertiles.
// Encode Q=4 / decode / max as R14.

#define D_FULL 512
#define M_SUB 64
#define KSUB 256
#define DSUB 8
#define KPB 512  // bytes per row (512 i8)

typedef int i32x4 __attribute__((ext_vector_type(4)));

static __device__ __forceinline__ unsigned int pack4i8(float a, float b,
                                                       float c, float d,
                                                       float s) {
  int q0 = (int)rintf(a * s), q1 = (int)rintf(b * s);
  int q2 = (int)rintf(c * s), q3 = (int)rintf(d * s);
  return (unsigned int)(q0 & 0xff) | ((unsigned int)(q1 & 0xff) << 8) |
         ((unsigned int)(q2 & 0xff) << 16) | ((unsigned int)(q3 & 0xff) << 24);
}

static __device__ __forceinline__ float scale_from(const float* part) {
  float m = 0.f;
#pragma unroll
  for (int i = 0; i < 64; ++i) m = fmaxf(m, part[i]);
  return 127.0f / m;
}

// ---------------- pass 0: per-block max|cen| (64 partials) ----------------
__global__ void max_kernel(const float* __restrict__ cen,
                           float* __restrict__ part) {
  const int t = threadIdx.x;
  const int i = (blockIdx.x * 256 + t) * 8;
  float4 a = *(const float4*)(cen + i);
  float4 b = *(const float4*)(cen + i + 4);
  float m = fmaxf(fmaxf(fmaxf(fabsf(a.x), fabsf(a.y)),
                        fmaxf(fabsf(a.z), fabsf(a.w))),
                  fmaxf(fmaxf(fabsf(b.x), fabsf(b.y)),
                        fmaxf(fabsf(b.z), fabsf(b.w))));
  __shared__ float wm[4];
  for (int off = 32; off; off >>= 1) m = fmaxf(m, __shfl_down(m, off, 64));
  if ((t & 63) == 0) wm[t >> 6] = m;
  __syncthreads();
  if (t == 0)
    part[blockIdx.x] = fmaxf(fmaxf(wm[0], wm[1]), fmaxf(wm[2], wm[3]));
}

// ---------------- encode queries -> A' (i8), Q=4, exact f32 argmin ----------
__global__ void encode_kernel(const float* __restrict__ x,
                              const float* __restrict__ cen,
                              signed char* __restrict__ Ap,
                              const float* __restrict__ part) {
  __shared__ float cs[KSUB][DSUB];
  __shared__ float n2[KSUB];
  const int t = threadIdx.x;
  const int sub = blockIdx.x;
  const int i0 = blockIdx.y * 1024 + t;

  const float* cp = cen + ((size_t)sub * KSUB + t) * DSUB;
  float4 c0 = *(const float4*)cp;
  float4 c1 = *(const float4*)(cp + 4);
  *(float4*)&cs[t][0] = c0;
  *(float4*)&cs[t][4] = c1;
  n2[t] = c0.x * c0.x + c0.y * c0.y + c0.z * c0.z + c0.w * c0.w +
          c1.x * c1.x + c1.y * c1.y + c1.z * c1.z + c1.w * c1.w;
  __syncthreads();

  float xq[4][8];
#pragma unroll
  for (int q = 0; q < 4; ++q) {
    const float* xp = x + (size_t)(i0 + q * 256) * D_FULL + sub * DSUB;
    *(float4*)&xq[q][0] = *(const float4*)xp;
    *(float4*)&xq[q][4] = *(const float4*)(xp + 4);
  }

  float best[4] = {1e30f, 1e30f, 1e30f, 1e30f};
  int bk[4] = {0, 0, 0, 0};
#pragma unroll 4
  for (int k = 0; k < KSUB; ++k) {
    float c[8];
    *(float4*)&c[0] = *(const float4*)&cs[k][0];
    *(float4*)&c[4] = *(const float4*)&cs[k][4];
    const float nn = n2[k];
#pragma unroll
    for (int q = 0; q < 4; ++q) {
      float dot = 0.f;
#pragma unroll
      for (int d = 0; d < 8; ++d) dot += c[d] * xq[q][d];
      float dis = nn - 2.0f * dot;
      if (dis < best[q]) { best[q] = dis; bk[q] = k; }  // strict < = numpy tie
    }
  }

  const float s = scale_from(part);
#pragma unroll
  for (int q = 0; q < 4; ++q) {
    const int b = bk[q];
    uint2 v;
    v.x = pack4i8(cs[b][0], cs[b][1], cs[b][2], cs[b][3], s);
    v.y = pack4i8(cs[b][4], cs[b][5], cs[b][6], cs[b][7], s);
    *(uint2*)(Ap + (size_t)(i0 + q * 256) * KPB + sub * DSUB) = v;
  }
}

// ---------------- decode targets -> B' (i8) ----------------
__global__ void decode_tgt(const int* __restrict__ tgt,
                           const float* __restrict__ cen,
                           signed char* __restrict__ Bp,
                           const float* __restrict__ part) {
  int g = blockIdx.x * 256 + threadIdx.x;
  int j = g >> 6, sub = g & 63;
  int k = tgt[g];
  const float* c = cen + ((size_t)sub * KSUB + k) * DSUB;
  float4 v0 = *(const float4*)c;
  float4 v1 = *(const float4*)(c + 4);
  const float s = scale_from(part);
  uint2 v;
  v.x = pack4i8(v0.x, v0.y, v0.z, v0.w, s);
  v.y = pack4i8(v1.x, v1.y, v1.z, v1.w, s);
  *(uint2*)(Bp + (size_t)j * KPB + sub * DSUB) = v;
}

// ---------------- GEMM: C = (A'q . B'q^T) / s^2 ----------------
// Slot (24 KB): A 256x64 i8 (16 KB) + B 128x64 i8 (8 KB). Row = 64 B =
// 4 chunks of 16 B. Phys chunk p at row r holds logical chunk p^(r&3)
// (stage: linear dest + inverse-swizzled global source, rule #21).
#define GLL(SRC, DST)                                                          \
  __builtin_amdgcn_global_load_lds(                                            \
      (const __attribute__((address_space(1))) void*)(SRC),                    \
      (__attribute__((address_space(3))) void*)(DST), 16, 0, 0)

#define STAGE(K0, SLOT)                                                        \
  do {                                                                         \
    signed char* as_ = lds + (SLOT)*24576;                                     \
    signed char* bs_ = as_ + 16384;                                            \
    _Pragma("unroll") for (int it = 0; it < 4; ++it) {                         \
      int r = it * 64 + (tid >> 2);                                            \
      int c = (tid & 3) ^ (r & 3);                                             \
      GLL(Ab + (size_t)r * KPB + (K0) + c * 16, as_ + it * 4096 + tid * 16);   \
    }                                                                          \
    _Pragma("unroll") for (int it = 0; it < 2; ++it) {                         \
      int r = it * 64 + (tid >> 2);                                            \
      int c = (tid & 3) ^ (r & 3);                                             \
      GLL(Bb + (size_t)r * KPB + (K0) + c * 16, bs_ + it * 4096 + tid * 16);   \
    }                                                                          \
  } while (0)

// One BK=64 step from SLOT: 12 ds_read_b128 + 32 MFMA i8 (K=64) per wave.
#define COMPUTE(SLOT)                                                          \
  do {                                                                         \
    const signed char* as_ = lds + (SLOT)*24576;                               \
    const signed char* bs_ = as_ + 16384;                                      \
    const int kq = l >> 4;                                                     \
    i32x4 a_[8], b_[4];                                                        \
    _Pragma("unroll") for (int i2 = 0; i2 < 8; ++i2) {                         \
      int row = wm * 128 + i2 * 16 + (l & 15);                                 \
      a_[i2] = *(const i32x4*)&as_[row * 64 + ((kq ^ (row & 3)) * 16)];        \
    }                                                                          \
    _Pragma("unroll") for (int j2 = 0; j2 < 4; ++j2) {                         \
      int row = wn * 64 + j2 * 16 + (l & 15);                                  \
      b_[j2] = *(const i32x4*)&bs_[row * 64 + ((kq ^ (row & 3)) * 16)];        \
    }                                                                          \
    __builtin_amdgcn_s_setprio(1);                                             \
    _Pragma("unroll") for (int i2 = 0; i2 < 8; ++i2)                           \
        _Pragma("unroll") for (int j2 = 0; j2 < 4; ++j2) acc[i2][j2] =         \
        __builtin_amdgcn_mfma_i32_16x16x64_i8(a_[i2], b_[j2], acc[i2][j2], 0,  \
                                              0, 0);                           \
    __builtin_amdgcn_s_setprio(0);                                             \
  } while (0)

#define VMW(N) asm volatile("s_waitcnt vmcnt(" #N ")" ::: "memory")
#define BAR() __builtin_amdgcn_s_barrier()

__global__ __launch_bounds__(256, 2) void gemm_i8(
    const signed char* __restrict__ A, const signed char* __restrict__ B,
    float* __restrict__ C, int Nt, const float* __restrict__ part) {
  __shared__ signed char lds[3 * 24576];  // 72 KB ring-of-3 -> 2 blocks/CU
  const int tid = threadIdx.x;
  const int w = tid >> 6, l = tid & 63;
  const int wm = w >> 1, wn = w & 1;  // 2M x 2N -> wave tile 128x64

  // XCD-pinned mapping: XCD x owns bn-stripe [x*16, x*16+16) (1 MB B i8,
  // L2-resident). Per XCD 16bm x 16bn; walk 4bm x 16bn supertiles bm-fastest.
  const int bid = blockIdx.x;
  const int xcd = bid & 7;
  const int idx = bid >> 3;                     // 0..255 per XCD
  const int bm = (idx >> 6) * 4 + (idx & 3);    // 0..15
  const int bn = xcd * 16 + ((idx >> 2) & 15);  // 0..127

  const signed char* Ab = A + (size_t)bm * 256 * KPB;
  const signed char* Bb = B + (size_t)bn * 128 * KPB;

  i32x4 acc[8][4] = {};

  // Ring-of-3, depth-2 prefetch, 6 loads/thread/tile (tile t in slot t%3).
  STAGE(0, 0);
  STAGE(64, 1);
  VMW(6);  // drain tile0's 6, leave tile1's 6 in flight
  BAR();

  // Step t: stage tile t+2 into slot (t+2)%3 (freed at step t-1's barrier),
  // compute tile t, drain tile t+1's 6 loads (leave t+2's 6 in flight).
  STAGE(128, 2); COMPUTE(0); VMW(6); BAR();  // t=0
  STAGE(192, 0); COMPUTE(1); VMW(6); BAR();  // t=1
  STAGE(256, 1); COMPUTE(2); VMW(6); BAR();  // t=2
  STAGE(320, 2); COMPUTE(0); VMW(6); BAR();  // t=3
  STAGE(384, 0); COMPUTE(1); VMW(6); BAR();  // t=4
  STAGE(448, 1); COMPUTE(2); VMW(6); BAR();  // t=5
  COMPUTE(0); VMW(0); BAR();                 // t=6 (drain tile 7)
  COMPUTE(1);                                // t=7

  // Epilogue: sim = acc * (max/127)^2. C/D layout col=lane&15,
  // row=(lane>>4)*4+reg (dtype-independent, m121-128).
  const float minv = 1.0f / scale_from(part);  // = max/127
  const float inv = minv * minv;
  const int rb = bm * 256 + wm * 128 + (l >> 4) * 4;
  const int cb = bn * 128 + wn * 64 + (l & 15);
#pragma unroll
  for (int i2 = 0; i2 < 8; ++i2)
#pragma unroll
    for (int j2 = 0; j2 < 4; ++j2)
#pragma unroll
      for (int r = 0; r < 4; ++r)
        C[(size_t)(rb + i2 * 16 + r) * Nt + cb + j2 * 16] =
            (float)acc[i2][j2][r] * inv;
}

extern "C" void kernel_launch(void* const* d_in, const int* in_sizes, int n_in,
                              void* d_out, int out_size, void* d_ws, size_t ws_size,
                              hipStream_t stream) {
  const float* x = (const float*)d_in[0];    // [n, 512]
  const float* cen = (const float*)d_in[1];  // [64, 256, 8]
  const int* tgt = (const int*)d_in[2];      // [m, 64]
  float* out = (float*)d_out;                // [n, m]
  const int n = in_sizes[0] / D_FULL;        // 4096
  const int m = in_sizes[2] / M_SUB;         // 16384

  signed char* Ap = (signed char*)d_ws;            // [n, 512] i8
  signed char* Bp = Ap + (size_t)n * KPB;          // [m, 512] i8
  float* part = (float*)(Bp + (size_t)m * KPB);    // [64] partial maxes

  max_kernel<<<dim3(64), 256, 0, stream>>>(cen, part);
  encode_kernel<<<dim3(M_SUB, n / 1024), 256, 0, stream>>>(x, cen, Ap, part);
  decode_tgt<<<dim3((m * M_SUB) / 256), 256, 0, stream>>>(tgt, cen, Bp, part);
  gemm_i8<<<dim3((n / 256) * (m / 128)), 256, 0, stream>>>(Ap, Bp, out, m, part);
}

// Round 20
// 96.647 us; speedup vs baseline: 1.1867x; 1.1241x over previous
//
#include <hip/hip_runtime.h>
#include <hip/hip_fp16.h>

// PQ sim: sim = decode(x) @ decode(tgt)^T via i8 GEMM (K=512, exact int32
// accumulate; global symmetric scale s = 127/max|cen| measured on device).
// R20: GEMM = R17 verbatim (best: 128x128, 4 waves, BK=64 i8, ring-of-3
// 48 KB + vmcnt(4), 3 blocks/CU, XOR swizzle, setprio, XCD-pinned).
// Preprocessing fused: encode(256 blocks) + decode(4096 blocks) in ONE
// launch (independent roles, block-level divergence) -> one fewer launch
// gap and co-execution across CUs.

#define D_FULL 512
#define M_SUB 64
#define KSUB 256
#define DSUB 8
#define KPB 512  // bytes per row (512 i8)

typedef int i32x4 __attribute__((ext_vector_type(4)));

static __device__ __forceinline__ unsigned int pack4i8(float a, float b,
                                                       float c, float d,
                                                       float s) {
  int q0 = (int)rintf(a * s), q1 = (int)rintf(b * s);
  int q2 = (int)rintf(c * s), q3 = (int)rintf(d * s);
  return (unsigned int)(q0 & 0xff) | ((unsigned int)(q1 & 0xff) << 8) |
         ((unsigned int)(q2 & 0xff) << 16) | ((unsigned int)(q3 & 0xff) << 24);
}

static __device__ __forceinline__ float scale_from(const float* part) {
  float m = 0.f;
#pragma unroll
  for (int i = 0; i < 64; ++i) m = fmaxf(m, part[i]);
  return 127.0f / m;
}

// ---------------- pass 0: per-block max|cen| (64 partials) ----------------
__global__ void max_kernel(const float* __restrict__ cen,
                           float* __restrict__ part) {
  const int t = threadIdx.x;
  const int i = (blockIdx.x * 256 + t) * 8;
  float4 a = *(const float4*)(cen + i);
  float4 b = *(const float4*)(cen + i + 4);
  float m = fmaxf(fmaxf(fmaxf(fabsf(a.x), fabsf(a.y)),
                        fmaxf(fabsf(a.z), fabsf(a.w))),
                  fmaxf(fmaxf(fabsf(b.x), fabsf(b.y)),
                        fmaxf(fabsf(b.z), fabsf(b.w))));
  __shared__ float wm[4];
  for (int off = 32; off; off >>= 1) m = fmaxf(m, __shfl_down(m, off, 64));
  if ((t & 63) == 0) wm[t >> 6] = m;
  __syncthreads();
  if (t == 0)
    part[blockIdx.x] = fmaxf(fmaxf(wm[0], wm[1]), fmaxf(wm[2], wm[3]));
}

// ---------------- fused encode (blocks 0..255) + decode (256..4351) --------
__global__ void prep_kernel(const float* __restrict__ x,
                            const float* __restrict__ cen,
                            const int* __restrict__ tgt,
                            signed char* __restrict__ Ap,
                            signed char* __restrict__ Bp,
                            const float* __restrict__ part) {
  const int bid = blockIdx.x;
  const int t = threadIdx.x;

  if (bid < 256) {
    // ---- encode role: Q=4, exact f32 argmin (identical to R17 encode) ----
    __shared__ float cs[KSUB][DSUB];
    __shared__ float n2[KSUB];
    const int sub = bid & 63;
    const int i0 = (bid >> 6) * 1024 + t;

    const float* cp = cen + ((size_t)sub * KSUB + t) * DSUB;
    float4 c0 = *(const float4*)cp;
    float4 c1 = *(const float4*)(cp + 4);
    *(float4*)&cs[t][0] = c0;
    *(float4*)&cs[t][4] = c1;
    n2[t] = c0.x * c0.x + c0.y * c0.y + c0.z * c0.z + c0.w * c0.w +
            c1.x * c1.x + c1.y * c1.y + c1.z * c1.z + c1.w * c1.w;
    __syncthreads();

    float xq[4][8];
#pragma unroll
    for (int q = 0; q < 4; ++q) {
      const float* xp = x + (size_t)(i0 + q * 256) * D_FULL + sub * DSUB;
      *(float4*)&xq[q][0] = *(const float4*)xp;
      *(float4*)&xq[q][4] = *(const float4*)(xp + 4);
    }

    float best[4] = {1e30f, 1e30f, 1e30f, 1e30f};
    int bk[4] = {0, 0, 0, 0};
#pragma unroll 4
    for (int k = 0; k < KSUB; ++k) {
      float c[8];
      *(float4*)&c[0] = *(const float4*)&cs[k][0];
      *(float4*)&c[4] = *(const float4*)&cs[k][4];
      const float nn = n2[k];
#pragma unroll
      for (int q = 0; q < 4; ++q) {
        float dot = 0.f;
#pragma unroll
        for (int d = 0; d < 8; ++d) dot += c[d] * xq[q][d];
        float dis = nn - 2.0f * dot;
        if (dis < best[q]) { best[q] = dis; bk[q] = k; }  // strict < = numpy
      }
    }

    const float s = scale_from(part);
#pragma unroll
    for (int q = 0; q < 4; ++q) {
      const int b = bk[q];
      uint2 v;
      v.x = pack4i8(cs[b][0], cs[b][1], cs[b][2], cs[b][3], s);
      v.y = pack4i8(cs[b][4], cs[b][5], cs[b][6], cs[b][7], s);
      *(uint2*)(Ap + (size_t)(i0 + q * 256) * KPB + sub * DSUB) = v;
    }
  } else {
    // ---- decode role (identical to R17 decode_tgt) ----
    int g = (bid - 256) * 256 + t;
    int j = g >> 6, sub = g & 63;
    int k = tgt[g];
    const float* c = cen + ((size_t)sub * KSUB + k) * DSUB;
    float4 v0 = *(const float4*)c;
    float4 v1 = *(const float4*)(c + 4);
    const float s = scale_from(part);
    uint2 v;
    v.x = pack4i8(v0.x, v0.y, v0.z, v0.w, s);
    v.y = pack4i8(v1.x, v1.y, v1.z, v1.w, s);
    *(uint2*)(Bp + (size_t)j * KPB + sub * DSUB) = v;
  }
}

// ---------------- GEMM: C = (A'q . B'q^T) / s^2 (R17 verbatim) -------------
// Slot (16 KB): A 128x64 i8 (8 KB) + B 128x64 i8 (8 KB). Row = 64 B =
// 4 chunks of 16 B. Phys chunk p at row r holds logical chunk p^(r&3)
// (stage: linear dest + inverse-swizzled global source, rule #21).
#define GLL(SRC, DST)                                                          \
  __builtin_amdgcn_global_load_lds(                                            \
      (const __attribute__((address_space(1))) void*)(SRC),                    \
      (__attribute__((address_space(3))) void*)(DST), 16, 0, 0)

#define STAGE(K0, SLOT)                                                        \
  do {                                                                         \
    signed char* as_ = lds + (SLOT)*16384;                                     \
    signed char* bs_ = as_ + 8192;                                             \
    _Pragma("unroll") for (int it = 0; it < 2; ++it) {                         \
      int r = it * 64 + (tid >> 2);                                            \
      int c = (tid & 3) ^ (r & 3);                                             \
      GLL(Ab + (size_t)r * KPB + (K0) + c * 16, as_ + it * 4096 + tid * 16);   \
    }                                                                          \
    _Pragma("unroll") for (int it = 0; it < 2; ++it) {                         \
      int r = it * 64 + (tid >> 2);                                            \
      int c = (tid & 3) ^ (r & 3);                                             \
      GLL(Bb + (size_t)r * KPB + (K0) + c * 16, bs_ + it * 4096 + tid * 16);   \
    }                                                                          \
  } while (0)

// One BK=64 step from SLOT: 8 ds_read_b128 + 16 MFMA i8 (K=64) per wave.
#define COMPUTE(SLOT)                                                          \
  do {                                                                         \
    const signed char* as_ = lds + (SLOT)*16384;                               \
    const signed char* bs_ = as_ + 8192;                                       \
    const int kq = l >> 4;                                                     \
    i32x4 a_[4], b_[4];                                                        \
    _Pragma("unroll") for (int i2 = 0; i2 < 4; ++i2) {                         \
      int row = wm * 64 + i2 * 16 + (l & 15);                                  \
      a_[i2] = *(const i32x4*)&as_[row * 64 + ((kq ^ (row & 3)) * 16)];        \
    }                                                                          \
    _Pragma("unroll") for (int j2 = 0; j2 < 4; ++j2) {                         \
      int row = wn * 64 + j2 * 16 + (l & 15);                                  \
      b_[j2] = *(const i32x4*)&bs_[row * 64 + ((kq ^ (row & 3)) * 16)];        \
    }                                                                          \
    __builtin_amdgcn_s_setprio(1);                                             \
    _Pragma("unroll") for (int i2 = 0; i2 < 4; ++i2)                           \
        _Pragma("unroll") for (int j2 = 0; j2 < 4; ++j2) acc[i2][j2] =         \
        __builtin_amdgcn_mfma_i32_16x16x64_i8(a_[i2], b_[j2], acc[i2][j2], 0,  \
                                              0, 0);                           \
    __builtin_amdgcn_s_setprio(0);                                             \
  } while (0)

#define VMW(N) asm volatile("s_waitcnt vmcnt(" #N ")" ::: "memory")
#define BAR() __builtin_amdgcn_s_barrier()

__global__ __launch_bounds__(256, 3) void gemm_i8(
    const signed char* __restrict__ A, const signed char* __restrict__ B,
    float* __restrict__ C, int Nt, const float* __restrict__ part) {
  __shared__ signed char lds[3 * 16384];  // 48 KB ring-of-3 -> 3 blocks/CU
  const int tid = threadIdx.x;
  const int w = tid >> 6, l = tid & 63;
  const int wm = w >> 1, wn = w & 1;  // 2M x 2N -> wave tile 64x64

  // XCD-pinned mapping: XCD x owns bn-stripe [x*16, x*16+16) (1 MB B i8,
  // L2-resident). Within XCD walk 4bm x 16bn supertiles bm-fastest.
  const int bid = blockIdx.x;
  const int xcd = bid & 7;
  const int idx = bid >> 3;                     // 0..511 per XCD
  const int sup = idx >> 6, loc = idx & 63;
  const int bm = sup * 4 + (loc & 3);           // 0..31
  const int bn = xcd * 16 + ((loc >> 2) & 15);  // 0..127

  const signed char* Ab = A + (size_t)bm * 128 * KPB;
  const signed char* Bb = B + (size_t)bn * 128 * KPB;

  i32x4 acc[4][4] = {};

  // Ring-of-3, depth-2 prefetch, 4 loads/thread/tile (tile t in slot t%3).
  STAGE(0, 0);
  STAGE(64, 1);
  VMW(4);  // drain tile0's 4, leave tile1's 4 in flight
  BAR();

  // Step t: stage tile t+2 into slot (t+2)%3 (freed at step t-1's barrier),
  // compute tile t, drain tile t+1's 4 loads (leave t+2's 4 in flight).
  STAGE(128, 2); COMPUTE(0); VMW(4); BAR();  // t=0
  STAGE(192, 0); COMPUTE(1); VMW(4); BAR();  // t=1
  STAGE(256, 1); COMPUTE(2); VMW(4); BAR();  // t=2
  STAGE(320, 2); COMPUTE(0); VMW(4); BAR();  // t=3
  STAGE(384, 0); COMPUTE(1); VMW(4); BAR();  // t=4
  STAGE(448, 1); COMPUTE(2); VMW(4); BAR();  // t=5
  COMPUTE(0); VMW(0); BAR();                 // t=6 (drain tile 7)
  COMPUTE(1);                                // t=7

  // Epilogue: sim = acc * (max/127)^2. C/D layout col=lane&15,
  // row=(lane>>4)*4+reg (dtype-independent, m121-128).
  const float minv = 1.0f / scale_from(part);  // = max/127
  const float inv = minv * minv;
  const int rb = bm * 128 + wm * 64 + (l >> 4) * 4;
  const int cb = bn * 128 + wn * 64 + (l & 15);
#pragma unroll
  for (int i2 = 0; i2 < 4; ++i2)
#pragma unroll
    for (int j2 = 0; j2 < 4; ++j2)
#pragma unroll
      for (int r = 0; r < 4; ++r)
        C[(size_t)(rb + i2 * 16 + r) * Nt + cb + j2 * 16] =
            (float)acc[i2][j2][r] * inv;
}

extern "C" void kernel_launch(void* const* d_in, const int* in_sizes, int n_in,
                              void* d_out, int out_size, void* d_ws, size_t ws_size,
                              hipStream_t stream) {
  const float* x = (const float*)d_in[0];    // [n, 512]
  const float* cen = (const float*)d_in[1];  // [64, 256, 8]
  const int* tgt = (const int*)d_in[2];      // [m, 64]
  float* out = (float*)d_out;                // [n, m]
  const int n = in_sizes[0] / D_FULL;        // 4096
  const int m = in_sizes[2] / M_SUB;         // 16384

  signed char* Ap = (signed char*)d_ws;            // [n, 512] i8
  signed char* Bp = Ap + (size_t)n * KPB;          // [m, 512] i8
  float* part = (float*)(Bp + (size_t)m * KPB);    // [64] partial maxes

  max_kernel<<<dim3(64), 256, 0, stream>>>(cen, part);
  prep_kernel<<<dim3(256 + (m * M_SUB) / 256), 256, 0, stream>>>(
      x, cen, tgt, Ap, Bp, part);
  gemm_i8<<<dim3((n / 128) * (m / 128)), 256, 0, stream>>>(Ap, Bp, out, m, part);
}